// Round 1
// baseline (5415.076 us; speedup 1.0000x reference)
//
#include <hip/hip_runtime.h>
#include <hip/hip_bf16.h>

#define BN_EPS 1e-5f

// ---------------------------------------------------------------------------
// Edge phase: msg = relu(x[src] + edge_attr@ew + eb); atomicAdd into agg[dst].
// One thread per edge. ew/eb staged in LDS (broadcast reads, conflict-free).
// ---------------------------------------------------------------------------
template<int DIN>
__global__ __launch_bounds__(256)
void edge_kernel(const float* __restrict__ xin,        // [N, DIN]
                 const float* __restrict__ edge_attr,  // [E, 8]
                 const int*   __restrict__ src_idx,    // [E]
                 const int*   __restrict__ dst_idx,    // [E]
                 const float* __restrict__ ew,         // [8, DIN]
                 const float* __restrict__ eb,         // [DIN]
                 float*       __restrict__ agg,        // [N, DIN] (zeroed)
                 int E) {
    __shared__ float s_ew[8 * DIN];
    __shared__ float s_eb[DIN];
    for (int i = threadIdx.x; i < 8 * DIN; i += 256) s_ew[i] = ew[i];
    if (threadIdx.x < DIN) s_eb[threadIdx.x] = eb[threadIdx.x];
    __syncthreads();

    int e = blockIdx.x * 256 + threadIdx.x;
    if (e >= E) return;

    const float4* eap = (const float4*)(edge_attr + (size_t)e * 8);
    float4 a0 = eap[0], a1 = eap[1];
    float ea[8] = {a0.x, a0.y, a0.z, a0.w, a1.x, a1.y, a1.z, a1.w};

    int s = src_idx[e];
    int d = dst_idx[e];

    float xr[DIN];
    const float4* xp = (const float4*)(xin + (size_t)s * DIN);
#pragma unroll
    for (int q = 0; q < DIN / 4; ++q) {
        float4 t = xp[q];
        xr[4 * q + 0] = t.x; xr[4 * q + 1] = t.y;
        xr[4 * q + 2] = t.z; xr[4 * q + 3] = t.w;
    }

    float* ag = agg + (size_t)d * DIN;
#pragma unroll
    for (int j = 0; j < DIN; ++j) {
        float v = s_eb[j];
#pragma unroll
        for (int k = 0; k < 8; ++k) v = fmaf(ea[k], s_ew[k * DIN + j], v);
        float m = xr[j] + v;
        m = m > 0.f ? m : 0.f;
        atomicAdd(&ag[j], m);
    }
}

// ---------------------------------------------------------------------------
// Node phase: h = relu(BN((x+agg)@wa + ba)); out = relu(h@wb + bb).
// One thread per node; all weights + folded BN scale/shift in LDS.
// ---------------------------------------------------------------------------
template<int DIN>
__global__ __launch_bounds__(256)
void node_kernel(const float* __restrict__ xin,   // [N, DIN]
                 const float* __restrict__ agg,   // [N, DIN]
                 const float* __restrict__ wa,    // [DIN, 16]
                 const float* __restrict__ ba,    // [16]
                 const float* __restrict__ g, const float* __restrict__ be,
                 const float* __restrict__ m, const float* __restrict__ v,
                 const float* __restrict__ wb,    // [16, 16]
                 const float* __restrict__ bb,    // [16]
                 float* __restrict__ hout,        // [N, 16]
                 int N) {
    __shared__ float s_wa[DIN * 16];
    __shared__ float s_wb[16 * 16];
    __shared__ float s_ba[16], s_scale[16], s_shift[16], s_bb[16];
    for (int i = threadIdx.x; i < DIN * 16; i += 256) s_wa[i] = wa[i];
    if (threadIdx.x < 256) s_wb[threadIdx.x] = wb[threadIdx.x];
    if (threadIdx.x < 16) {
        int j = threadIdx.x;
        s_ba[j] = ba[j];
        float sc = g[j] * rsqrtf(v[j] + BN_EPS);
        s_scale[j] = sc;
        s_shift[j] = be[j] - m[j] * sc;
        s_bb[j] = bb[j];
    }
    __syncthreads();

    int i = blockIdx.x * 256 + threadIdx.x;
    if (i >= N) return;

    float s[DIN];
    const float4* xp = (const float4*)(xin + (size_t)i * DIN);
    const float4* ap = (const float4*)(agg + (size_t)i * DIN);
#pragma unroll
    for (int q = 0; q < DIN / 4; ++q) {
        float4 tx = xp[q], ta = ap[q];
        s[4 * q + 0] = tx.x + ta.x; s[4 * q + 1] = tx.y + ta.y;
        s[4 * q + 2] = tx.z + ta.z; s[4 * q + 3] = tx.w + ta.w;
    }

    float h[16];
#pragma unroll
    for (int j = 0; j < 16; ++j) {
        float acc = s_ba[j];
#pragma unroll
        for (int k = 0; k < DIN; ++k) acc = fmaf(s[k], s_wa[k * 16 + j], acc);
        acc = acc * s_scale[j] + s_shift[j];
        h[j] = acc > 0.f ? acc : 0.f;
    }

    float* op = hout + (size_t)i * 16;
#pragma unroll
    for (int j4 = 0; j4 < 4; ++j4) {
        float4 o;
        float* oe = (float*)&o;
#pragma unroll
        for (int t = 0; t < 4; ++t) {
            int j = j4 * 4 + t;
            float acc = s_bb[j];
#pragma unroll
            for (int k = 0; k < 16; ++k) acc = fmaf(h[k], s_wb[k * 16 + j], acc);
            oe[t] = acc > 0.f ? acc : 0.f;
        }
        ((float4*)op)[j4] = o;
    }
}

// ---------------------------------------------------------------------------
// Head: out = relu(concat(h1,h2,h3) @ lw1 + lb1) @ lw2 + lb2.
// One thread per node; lw1 (12 KB) in LDS, accumulate 4 outputs directly.
// ---------------------------------------------------------------------------
__global__ __launch_bounds__(256)
void final_kernel(const float* __restrict__ h1, const float* __restrict__ h2,
                  const float* __restrict__ h3,
                  const float* __restrict__ lw1, const float* __restrict__ lb1,
                  const float* __restrict__ lw2, const float* __restrict__ lb2,
                  float* __restrict__ out, int N) {
    __shared__ float s_lw1[48 * 64];
    __shared__ float s_lw2[64 * 4];
    __shared__ float s_lb1[64];
    __shared__ float s_lb2[4];
    for (int i = threadIdx.x; i < 48 * 64; i += 256) s_lw1[i] = lw1[i];
    if (threadIdx.x < 256) s_lw2[threadIdx.x] = lw2[threadIdx.x];
    if (threadIdx.x < 64) s_lb1[threadIdx.x] = lb1[threadIdx.x];
    if (threadIdx.x < 4) s_lb2[threadIdx.x] = lb2[threadIdx.x];
    __syncthreads();

    int i = blockIdx.x * 256 + threadIdx.x;
    if (i >= N) return;

    float c[48];
    const float4* p1 = (const float4*)(h1 + (size_t)i * 16);
    const float4* p2 = (const float4*)(h2 + (size_t)i * 16);
    const float4* p3 = (const float4*)(h3 + (size_t)i * 16);
#pragma unroll
    for (int q = 0; q < 4; ++q) {
        float4 t = p1[q];
        c[4 * q + 0] = t.x; c[4 * q + 1] = t.y; c[4 * q + 2] = t.z; c[4 * q + 3] = t.w;
    }
#pragma unroll
    for (int q = 0; q < 4; ++q) {
        float4 t = p2[q];
        c[16 + 4 * q + 0] = t.x; c[16 + 4 * q + 1] = t.y; c[16 + 4 * q + 2] = t.z; c[16 + 4 * q + 3] = t.w;
    }
#pragma unroll
    for (int q = 0; q < 4; ++q) {
        float4 t = p3[q];
        c[32 + 4 * q + 0] = t.x; c[32 + 4 * q + 1] = t.y; c[32 + 4 * q + 2] = t.z; c[32 + 4 * q + 3] = t.w;
    }

    float o0 = s_lb2[0], o1 = s_lb2[1], o2 = s_lb2[2], o3 = s_lb2[3];
#pragma unroll 8
    for (int j = 0; j < 64; ++j) {
        float t = s_lb1[j];
#pragma unroll
        for (int k = 0; k < 48; ++k) t = fmaf(c[k], s_lw1[k * 64 + j], t);
        t = t > 0.f ? t : 0.f;
        o0 = fmaf(t, s_lw2[j * 4 + 0], o0);
        o1 = fmaf(t, s_lw2[j * 4 + 1], o1);
        o2 = fmaf(t, s_lw2[j * 4 + 2], o2);
        o3 = fmaf(t, s_lw2[j * 4 + 3], o3);
    }
    float4 o = {o0, o1, o2, o3};
    ((float4*)(out + (size_t)i * 4))[0] = o;
}

// ---------------------------------------------------------------------------
// Launch
// ---------------------------------------------------------------------------
extern "C" void kernel_launch(void* const* d_in, const int* in_sizes, int n_in,
                              void* d_out, int out_size, void* d_ws, size_t ws_size,
                              hipStream_t stream) {
    const float* x  = (const float*)d_in[0];
    const int*   ei = (const int*)d_in[1];
    const float* ea = (const float*)d_in[2];
    const int N = in_sizes[0] / 32;
    const int E = in_sizes[1] / 2;
    const int* srci = ei;
    const int* dsti = ei + E;

    // Layer param base indices: c=1 -> 3, c=2 -> 13, c=3 -> 23
    // order: ew, eb, wa, ba, g, be, m, v, wb, bb
    const float* lw1 = (const float*)d_in[33];
    const float* lb1 = (const float*)d_in[34];
    const float* lw2 = (const float*)d_in[35];
    const float* lb2 = (const float*)d_in[36];

    float* ws  = (float*)d_ws;
    float* agg = ws;                          // reused: max N*32 floats
    float* h1  = ws + (size_t)N * 32;         // N*16
    float* h2  = h1 + (size_t)N * 16;         // N*16
    float* h3  = h2 + (size_t)N * 16;         // N*16

    const int eblocks = (E + 255) / 256;
    const int nblocks = (N + 255) / 256;

    // ---- Layer 1 (din = 32) ----
    hipMemsetAsync(agg, 0, (size_t)N * 32 * sizeof(float), stream);
    edge_kernel<32><<<eblocks, 256, 0, stream>>>(
        x, ea, srci, dsti,
        (const float*)d_in[3], (const float*)d_in[4], agg, E);
    node_kernel<32><<<nblocks, 256, 0, stream>>>(
        x, agg,
        (const float*)d_in[5], (const float*)d_in[6],
        (const float*)d_in[7], (const float*)d_in[8],
        (const float*)d_in[9], (const float*)d_in[10],
        (const float*)d_in[11], (const float*)d_in[12], h1, N);

    // ---- Layer 2 (din = 16) ----
    hipMemsetAsync(agg, 0, (size_t)N * 16 * sizeof(float), stream);
    edge_kernel<16><<<eblocks, 256, 0, stream>>>(
        h1, ea, srci, dsti,
        (const float*)d_in[13], (const float*)d_in[14], agg, E);
    node_kernel<16><<<nblocks, 256, 0, stream>>>(
        h1, agg,
        (const float*)d_in[15], (const float*)d_in[16],
        (const float*)d_in[17], (const float*)d_in[18],
        (const float*)d_in[19], (const float*)d_in[20],
        (const float*)d_in[21], (const float*)d_in[22], h2, N);

    // ---- Layer 3 (din = 16) ----
    hipMemsetAsync(agg, 0, (size_t)N * 16 * sizeof(float), stream);
    edge_kernel<16><<<eblocks, 256, 0, stream>>>(
        h2, ea, srci, dsti,
        (const float*)d_in[23], (const float*)d_in[24], agg, E);
    node_kernel<16><<<nblocks, 256, 0, stream>>>(
        h2, agg,
        (const float*)d_in[25], (const float*)d_in[26],
        (const float*)d_in[27], (const float*)d_in[28],
        (const float*)d_in[29], (const float*)d_in[30],
        (const float*)d_in[31], (const float*)d_in[32], h3, N);

    // ---- Head ----
    final_kernel<<<nblocks, 256, 0, stream>>>(
        h1, h2, h3, lw1, lb1, lw2, lb2, (float*)d_out, N);
}

// Round 2
// 649.715 us; speedup vs baseline: 8.3345x; 8.3345x over previous
//
#include <hip/hip_runtime.h>
#include <hip/hip_bf16.h>

#define BN_EPS 1e-5f

// ===========================================================================
// Preprocessing: counting sort of edges by dst -> CSR + permuted src/edge_attr
// ===========================================================================

__global__ __launch_bounds__(256)
void hist_kernel(const int* __restrict__ dst_idx, int* __restrict__ deg, int E) {
    int e = blockIdx.x * 256 + threadIdx.x;
    if (e < E) atomicAdd(&deg[dst_idx[e]], 1);
}

// Per-chunk sums (chunk = 256 elems)
__global__ __launch_bounds__(256)
void blocksum_kernel(const int* __restrict__ deg, int* __restrict__ bsum, int N) {
    __shared__ int tmp[256];
    int i = blockIdx.x * 256 + threadIdx.x;
    int v = (i < N) ? deg[i] : 0;
    tmp[threadIdx.x] = v;
    __syncthreads();
    for (int off = 128; off > 0; off >>= 1) {
        if (threadIdx.x < off) tmp[threadIdx.x] += tmp[threadIdx.x + off];
        __syncthreads();
    }
    if (threadIdx.x == 0) bsum[blockIdx.x] = tmp[0];
}

// Single-block exclusive scan of chunk sums (nchunks <= 512)
__global__ __launch_bounds__(512)
void scanblocks_kernel(const int* __restrict__ bsum, int* __restrict__ boff,
                       int nchunks, int* __restrict__ rowstart, int N, int E) {
    __shared__ int tmp[512];
    int t = threadIdx.x;
    tmp[t] = (t < nchunks) ? bsum[t] : 0;
    __syncthreads();
    for (int off = 1; off < 512; off <<= 1) {
        int add = (t >= off) ? tmp[t - off] : 0;
        __syncthreads();
        tmp[t] += add;
        __syncthreads();
    }
    if (t < nchunks) boff[t] = (t == 0) ? 0 : tmp[t - 1];
    if (t == 0) rowstart[N] = E;
}

// Final per-chunk exclusive scan + chunk offset -> rowstart
__global__ __launch_bounds__(256)
void scanfinal_kernel(const int* __restrict__ deg, const int* __restrict__ boff,
                      int* __restrict__ rowstart, int N) {
    __shared__ int tmp[256];
    int i = blockIdx.x * 256 + threadIdx.x;
    int t = threadIdx.x;
    int v = (i < N) ? deg[i] : 0;
    tmp[t] = v;
    __syncthreads();
    for (int off = 1; off < 256; off <<= 1) {
        int add = (t >= off) ? tmp[t - off] : 0;
        __syncthreads();
        tmp[t] += add;
        __syncthreads();
    }
    if (i < N) rowstart[i] = boff[blockIdx.x] + tmp[t] - v;  // exclusive
}

// Scatter edges into dst-sorted order; permute src and edge_attr.
__global__ __launch_bounds__(256)
void scatter_kernel(const int* __restrict__ src_idx, const int* __restrict__ dst_idx,
                    const float* __restrict__ edge_attr,
                    int* __restrict__ cursor,
                    int* __restrict__ src_sorted, float* __restrict__ ea_sorted,
                    int E) {
    int e = blockIdx.x * 256 + threadIdx.x;
    if (e >= E) return;
    int d = dst_idx[e];
    int pos = atomicAdd(&cursor[d], 1);
    src_sorted[pos] = src_idx[e];
    const float4* eap = (const float4*)(edge_attr + (size_t)e * 8);
    float4 a0 = eap[0], a1 = eap[1];
    float4* op = (float4*)(ea_sorted + (size_t)pos * 8);
    op[0] = a0;
    op[1] = a1;
}

// ===========================================================================
// Fused GINE layer: per-node gather-aggregate (no atomics) + Linear/BN/ReLU/
// Linear/ReLU node transform.
// ===========================================================================
template<int DIN>
__global__ __launch_bounds__(256)
void gine_layer(const float* __restrict__ xin,        // [N, DIN]
                const int*   __restrict__ rowstart,   // [N+1]
                const int*   __restrict__ src_sorted, // [E]
                const float* __restrict__ ea_sorted,  // [E, 8]
                const float* __restrict__ ew,         // [8, DIN]
                const float* __restrict__ eb,         // [DIN]
                const float* __restrict__ wa,         // [DIN, 16]
                const float* __restrict__ ba,         // [16]
                const float* __restrict__ g, const float* __restrict__ be,
                const float* __restrict__ m, const float* __restrict__ v,
                const float* __restrict__ wb,         // [16, 16]
                const float* __restrict__ bb,         // [16]
                float* __restrict__ hout,             // [N, 16]
                int N) {
    __shared__ float s_ew[8 * DIN];
    __shared__ float s_eb[DIN];
    __shared__ float s_wa[DIN * 16];
    __shared__ float s_wb[16 * 16];
    __shared__ float s_ba[16], s_scale[16], s_shift[16], s_bb[16];
    for (int i = threadIdx.x; i < 8 * DIN; i += 256) s_ew[i] = ew[i];
    for (int i = threadIdx.x; i < DIN * 16; i += 256) s_wa[i] = wa[i];
    if (threadIdx.x < 256) s_wb[threadIdx.x] = wb[threadIdx.x];
    if (threadIdx.x < DIN) s_eb[threadIdx.x] = eb[threadIdx.x];
    if (threadIdx.x < 16) {
        int j = threadIdx.x;
        s_ba[j] = ba[j];
        float sc = g[j] * rsqrtf(v[j] + BN_EPS);
        s_scale[j] = sc;
        s_shift[j] = be[j] - m[j] * sc;
        s_bb[j] = bb[j];
    }
    __syncthreads();

    int i = blockIdx.x * 256 + threadIdx.x;
    if (i >= N) return;

    int e0 = rowstart[i];
    int e1 = rowstart[i + 1];

    float acc[DIN];
#pragma unroll
    for (int j = 0; j < DIN; ++j) acc[j] = 0.f;

    for (int e = e0; e < e1; ++e) {
        int s = src_sorted[e];
        const float4* eap = (const float4*)(ea_sorted + (size_t)e * 8);
        float4 a0 = eap[0], a1 = eap[1];
        float ea[8] = {a0.x, a0.y, a0.z, a0.w, a1.x, a1.y, a1.z, a1.w};

        const float4* xp = (const float4*)(xin + (size_t)s * DIN);
        float xr[DIN];
#pragma unroll
        for (int q = 0; q < DIN / 4; ++q) {
            float4 t = xp[q];
            xr[4 * q + 0] = t.x; xr[4 * q + 1] = t.y;
            xr[4 * q + 2] = t.z; xr[4 * q + 3] = t.w;
        }
#pragma unroll
        for (int j = 0; j < DIN; ++j) {
            float lin = s_eb[j];
#pragma unroll
            for (int k = 0; k < 8; ++k) lin = fmaf(ea[k], s_ew[k * DIN + j], lin);
            float msg = xr[j] + lin;
            acc[j] += (msg > 0.f ? msg : 0.f);
        }
    }

    // node transform: s = x_i + acc
    float s[DIN];
    const float4* xp = (const float4*)(xin + (size_t)i * DIN);
#pragma unroll
    for (int q = 0; q < DIN / 4; ++q) {
        float4 t = xp[q];
        s[4 * q + 0] = t.x + acc[4 * q + 0];
        s[4 * q + 1] = t.y + acc[4 * q + 1];
        s[4 * q + 2] = t.z + acc[4 * q + 2];
        s[4 * q + 3] = t.w + acc[4 * q + 3];
    }

    float h[16];
#pragma unroll
    for (int j = 0; j < 16; ++j) {
        float a = s_ba[j];
#pragma unroll
        for (int k = 0; k < DIN; ++k) a = fmaf(s[k], s_wa[k * 16 + j], a);
        a = a * s_scale[j] + s_shift[j];
        h[j] = a > 0.f ? a : 0.f;
    }

    float* op = hout + (size_t)i * 16;
#pragma unroll
    for (int j4 = 0; j4 < 4; ++j4) {
        float4 o;
        float* oe = (float*)&o;
#pragma unroll
        for (int t = 0; t < 4; ++t) {
            int j = j4 * 4 + t;
            float a = s_bb[j];
#pragma unroll
            for (int k = 0; k < 16; ++k) a = fmaf(h[k], s_wb[k * 16 + j], a);
            oe[t] = a > 0.f ? a : 0.f;
        }
        ((float4*)op)[j4] = o;
    }
}

// ===========================================================================
// Head: out = relu(concat(h1,h2,h3) @ lw1 + lb1) @ lw2 + lb2.
// ===========================================================================
__global__ __launch_bounds__(256)
void final_kernel(const float* __restrict__ h1, const float* __restrict__ h2,
                  const float* __restrict__ h3,
                  const float* __restrict__ lw1, const float* __restrict__ lb1,
                  const float* __restrict__ lw2, const float* __restrict__ lb2,
                  float* __restrict__ out, int N) {
    __shared__ float s_lw1[48 * 64];
    __shared__ float s_lw2[64 * 4];
    __shared__ float s_lb1[64];
    __shared__ float s_lb2[4];
    for (int i = threadIdx.x; i < 48 * 64; i += 256) s_lw1[i] = lw1[i];
    if (threadIdx.x < 256) s_lw2[threadIdx.x] = lw2[threadIdx.x];
    if (threadIdx.x < 64) s_lb1[threadIdx.x] = lb1[threadIdx.x];
    if (threadIdx.x < 4) s_lb2[threadIdx.x] = lb2[threadIdx.x];
    __syncthreads();

    int i = blockIdx.x * 256 + threadIdx.x;
    if (i >= N) return;

    float c[48];
    const float4* p1 = (const float4*)(h1 + (size_t)i * 16);
    const float4* p2 = (const float4*)(h2 + (size_t)i * 16);
    const float4* p3 = (const float4*)(h3 + (size_t)i * 16);
#pragma unroll
    for (int q = 0; q < 4; ++q) {
        float4 t = p1[q];
        c[4 * q + 0] = t.x; c[4 * q + 1] = t.y; c[4 * q + 2] = t.z; c[4 * q + 3] = t.w;
    }
#pragma unroll
    for (int q = 0; q < 4; ++q) {
        float4 t = p2[q];
        c[16 + 4 * q] = t.x; c[17 + 4 * q] = t.y; c[18 + 4 * q] = t.z; c[19 + 4 * q] = t.w;
    }
#pragma unroll
    for (int q = 0; q < 4; ++q) {
        float4 t = p3[q];
        c[32 + 4 * q] = t.x; c[33 + 4 * q] = t.y; c[34 + 4 * q] = t.z; c[35 + 4 * q] = t.w;
    }

    float o0 = s_lb2[0], o1 = s_lb2[1], o2 = s_lb2[2], o3 = s_lb2[3];
#pragma unroll 8
    for (int j = 0; j < 64; ++j) {
        float t = s_lb1[j];
#pragma unroll
        for (int k = 0; k < 48; ++k) t = fmaf(c[k], s_lw1[k * 64 + j], t);
        t = t > 0.f ? t : 0.f;
        o0 = fmaf(t, s_lw2[j * 4 + 0], o0);
        o1 = fmaf(t, s_lw2[j * 4 + 1], o1);
        o2 = fmaf(t, s_lw2[j * 4 + 2], o2);
        o3 = fmaf(t, s_lw2[j * 4 + 3], o3);
    }
    float4 o = {o0, o1, o2, o3};
    ((float4*)(out + (size_t)i * 4))[0] = o;
}

// ===========================================================================
// Launch
// ===========================================================================
extern "C" void kernel_launch(void* const* d_in, const int* in_sizes, int n_in,
                              void* d_out, int out_size, void* d_ws, size_t ws_size,
                              hipStream_t stream) {
    const float* x  = (const float*)d_in[0];
    const int*   ei = (const int*)d_in[1];
    const float* ea = (const float*)d_in[2];
    const int N = in_sizes[0] / 32;
    const int E = in_sizes[1] / 2;
    const int* srci = ei;
    const int* dsti = ei + E;

    const float* lw1 = (const float*)d_in[33];
    const float* lb1 = (const float*)d_in[34];
    const float* lw2 = (const float*)d_in[35];
    const float* lb2 = (const float*)d_in[36];

    const int nchunks = (N + 255) / 256;
    const int eblocks = (E + 255) / 256;

    // Workspace layout (all 16B-aligned chunks):
    char* p = (char*)d_ws;
    int*   rowstart   = (int*)p;            p += (size_t)(N + 1 + 3) / 4 * 16;
    int*   cursor     = (int*)p;            p += (size_t)(N + 3) / 4 * 16;      // doubles as deg
    int*   bsum       = (int*)p;            p += (size_t)(nchunks + 3) / 4 * 16;
    int*   boff       = (int*)p;            p += (size_t)(nchunks + 3) / 4 * 16;
    int*   src_sorted = (int*)p;            p += (size_t)E * 4;
    float* ea_sorted  = (float*)p;          p += (size_t)E * 8 * 4;
    float* h1         = (float*)p;          p += (size_t)N * 16 * 4;
    float* h2         = (float*)p;          p += (size_t)N * 16 * 4;
    float* h3         = (float*)p;          p += (size_t)N * 16 * 4;

    int* deg = cursor;

    // ---- Build CSR (counting sort by dst) ----
    hipMemsetAsync(deg, 0, (size_t)N * sizeof(int), stream);
    hist_kernel<<<eblocks, 256, 0, stream>>>(dsti, deg, E);
    blocksum_kernel<<<nchunks, 256, 0, stream>>>(deg, bsum, N);
    scanblocks_kernel<<<1, 512, 0, stream>>>(bsum, boff, nchunks, rowstart, N, E);
    scanfinal_kernel<<<nchunks, 256, 0, stream>>>(deg, boff, rowstart, N);
    hipMemcpyAsync(cursor, rowstart, (size_t)N * sizeof(int),
                   hipMemcpyDeviceToDevice, stream);
    scatter_kernel<<<eblocks, 256, 0, stream>>>(srci, dsti, ea, cursor,
                                                src_sorted, ea_sorted, E);

    // ---- Layers ----
    gine_layer<32><<<nchunks, 256, 0, stream>>>(
        x, rowstart, src_sorted, ea_sorted,
        (const float*)d_in[3], (const float*)d_in[4],
        (const float*)d_in[5], (const float*)d_in[6],
        (const float*)d_in[7], (const float*)d_in[8],
        (const float*)d_in[9], (const float*)d_in[10],
        (const float*)d_in[11], (const float*)d_in[12], h1, N);

    gine_layer<16><<<nchunks, 256, 0, stream>>>(
        h1, rowstart, src_sorted, ea_sorted,
        (const float*)d_in[13], (const float*)d_in[14],
        (const float*)d_in[15], (const float*)d_in[16],
        (const float*)d_in[17], (const float*)d_in[18],
        (const float*)d_in[19], (const float*)d_in[20],
        (const float*)d_in[21], (const float*)d_in[22], h2, N);

    gine_layer<16><<<nchunks, 256, 0, stream>>>(
        h2, rowstart, src_sorted, ea_sorted,
        (const float*)d_in[23], (const float*)d_in[24],
        (const float*)d_in[25], (const float*)d_in[26],
        (const float*)d_in[27], (const float*)d_in[28],
        (const float*)d_in[29], (const float*)d_in[30],
        (const float*)d_in[31], (const float*)d_in[32], h3, N);

    // ---- Head ----
    final_kernel<<<nchunks, 256, 0, stream>>>(
        h1, h2, h3, lw1, lb1, lw2, lb2, (float*)d_out, N);
}

// Round 3
// 639.636 us; speedup vs baseline: 8.4659x; 1.0158x over previous
//
#include <hip/hip_runtime.h>
#include <hip/hip_bf16.h>

#define BN_EPS 1e-5f

// ===========================================================================
// Preprocessing: counting sort of edges by dst -> CSR + permuted src/edge_attr
// ===========================================================================

__global__ __launch_bounds__(256)
void hist_kernel(const int* __restrict__ dst_idx, int* __restrict__ deg, int E) {
    int e = blockIdx.x * 256 + threadIdx.x;
    if (e < E) atomicAdd(&deg[dst_idx[e]], 1);
}

// Per-chunk sums (chunk = 256 elems)
__global__ __launch_bounds__(256)
void blocksum_kernel(const int* __restrict__ deg, int* __restrict__ bsum, int N) {
    __shared__ int tmp[256];
    int i = blockIdx.x * 256 + threadIdx.x;
    int v = (i < N) ? deg[i] : 0;
    tmp[threadIdx.x] = v;
    __syncthreads();
    for (int off = 128; off > 0; off >>= 1) {
        if (threadIdx.x < off) tmp[threadIdx.x] += tmp[threadIdx.x + off];
        __syncthreads();
    }
    if (threadIdx.x == 0) bsum[blockIdx.x] = tmp[0];
}

// Single-block exclusive scan of chunk sums (nchunks <= 512)
__global__ __launch_bounds__(512)
void scanblocks_kernel(const int* __restrict__ bsum, int* __restrict__ boff,
                       int nchunks, int* __restrict__ rowstart, int N, int E) {
    __shared__ int tmp[512];
    int t = threadIdx.x;
    tmp[t] = (t < nchunks) ? bsum[t] : 0;
    __syncthreads();
    for (int off = 1; off < 512; off <<= 1) {
        int add = (t >= off) ? tmp[t - off] : 0;
        __syncthreads();
        tmp[t] += add;
        __syncthreads();
    }
    if (t < nchunks) boff[t] = (t == 0) ? 0 : tmp[t - 1];
    if (t == 0) rowstart[N] = E;
}

// Final per-chunk exclusive scan + chunk offset -> rowstart AND cursor copy
__global__ __launch_bounds__(256)
void scanfinal_kernel(const int* __restrict__ deg, const int* __restrict__ boff,
                      int* __restrict__ rowstart, int* __restrict__ cursor, int N) {
    __shared__ int tmp[256];
    int i = blockIdx.x * 256 + threadIdx.x;
    int t = threadIdx.x;
    int v = (i < N) ? deg[i] : 0;
    tmp[t] = v;
    __syncthreads();
    for (int off = 1; off < 256; off <<= 1) {
        int add = (t >= off) ? tmp[t - off] : 0;
        __syncthreads();
        tmp[t] += add;
        __syncthreads();
    }
    if (i < N) {
        int rs = boff[blockIdx.x] + tmp[t] - v;  // exclusive
        rowstart[i] = rs;
        cursor[i] = rs;   // deg aliases cursor: overwrite after read is safe
    }
}

// Scatter edge ids into dst-sorted order (light: 8 B/edge random writes).
__global__ __launch_bounds__(256)
void scatter_kernel(const int* __restrict__ src_idx, const int* __restrict__ dst_idx,
                    int* __restrict__ cursor,
                    int* __restrict__ src_sorted, int* __restrict__ eid_sorted,
                    int E) {
    int e = blockIdx.x * 256 + threadIdx.x;
    if (e >= E) return;
    int d = dst_idx[e];
    int pos = atomicAdd(&cursor[d], 1);
    src_sorted[pos] = src_idx[e];
    eid_sorted[pos] = e;
}

// Gather-permute edge_attr: coalesced 32 B writes, random 32 B reads (L3-served).
__global__ __launch_bounds__(256)
void permute_ea_kernel(const float* __restrict__ edge_attr,
                       const int* __restrict__ eid_sorted,
                       float* __restrict__ ea_sorted, int E) {
    int e = blockIdx.x * 256 + threadIdx.x;
    if (e >= E) return;
    int id = eid_sorted[e];
    const float4* sp = (const float4*)(edge_attr + (size_t)id * 8);
    float4 a0 = sp[0], a1 = sp[1];
    float4* dp = (float4*)(ea_sorted + (size_t)e * 8);
    dp[0] = a0;
    dp[1] = a1;
}

// ===========================================================================
// Fused GINE layer, channel-parallel: LPN = DIN/4 lanes per node, each lane
// owns 4 channels. Aggregate in registers (no atomics), node transform via
// LDS staging with padded strides.
// ===========================================================================
template<int DIN, int LPN>
__global__ __launch_bounds__(256)
void gine_layer(const float* __restrict__ xin,        // [N, DIN]
                const int*   __restrict__ rowstart,   // [N+1]
                const int*   __restrict__ src_sorted, // [E]
                const float* __restrict__ ea_sorted,  // [E, 8]
                const float* __restrict__ ew,         // [8, DIN]
                const float* __restrict__ eb,         // [DIN]
                const float* __restrict__ wa,         // [DIN, 16]
                const float* __restrict__ ba,         // [16]
                const float* __restrict__ g, const float* __restrict__ be,
                const float* __restrict__ m, const float* __restrict__ v,
                const float* __restrict__ wb,         // [16, 16]
                const float* __restrict__ bb,         // [16]
                float* __restrict__ hout,             // [N, 16]
                int N) {
    static_assert(DIN / LPN == 4, "4 channels per lane");
    constexpr int NPB = 256 / LPN;   // nodes per block
    constexpr int OC  = 16 / LPN;    // transform outputs per lane

    __shared__ float s_wa[DIN * 16];
    __shared__ float s_wb[16 * 16];
    __shared__ float s_ba[16], s_scale[16], s_shift[16], s_bb[16];
    __shared__ float s_s[NPB][DIN + 1];   // padded: conflict-free transform reads
    __shared__ float s_h[NPB][17];

    int t = threadIdx.x;
    for (int idx = t; idx < DIN * 16; idx += 256) s_wa[idx] = wa[idx];
    s_wb[t] = wb[t];
    if (t < 16) {
        s_ba[t] = ba[t];
        float sc = g[t] * rsqrtf(v[t] + BN_EPS);
        s_scale[t] = sc;
        s_shift[t] = be[t] - m[t] * sc;
        s_bb[t] = bb[t];
    }
    // (first LDS read of weights happens after the post-aggregation barrier)

    int nl   = t / LPN;
    int lane = t % LPN;
    int i    = blockIdx.x * NPB + nl;
    int c0   = lane * 4;

    // Hoist this lane's ew columns + eb into registers (global, cached reads).
    float ew_r[8][4];
#pragma unroll
    for (int k = 0; k < 8; ++k) {
        float4 w = *(const float4*)(ew + k * DIN + c0);
        ew_r[k][0] = w.x; ew_r[k][1] = w.y; ew_r[k][2] = w.z; ew_r[k][3] = w.w;
    }
    float4 ebv = *(const float4*)(eb + c0);
    float eb_r[4] = {ebv.x, ebv.y, ebv.z, ebv.w};

    float acc[4] = {0.f, 0.f, 0.f, 0.f};
    if (i < N) {
        int e0 = rowstart[i];
        int e1 = rowstart[i + 1];
        for (int e = e0; e < e1; ++e) {
            int s = src_sorted[e];
            const float4* eap = (const float4*)(ea_sorted + (size_t)e * 8);
            float4 a0 = eap[0], a1 = eap[1];
            float4 xv = *(const float4*)(xin + (size_t)s * DIN + c0);
            float av[8] = {a0.x, a0.y, a0.z, a0.w, a1.x, a1.y, a1.z, a1.w};
            float xr[4] = {xv.x, xv.y, xv.z, xv.w};
#pragma unroll
            for (int j = 0; j < 4; ++j) {
                float lin = eb_r[j];
#pragma unroll
                for (int k = 0; k < 8; ++k) lin = fmaf(av[k], ew_r[k][j], lin);
                float msg = xr[j] + lin;
                acc[j] += (msg > 0.f ? msg : 0.f);
            }
        }
        // s = x_i + acc -> LDS
        float4 xi = *(const float4*)(xin + (size_t)i * DIN + c0);
        s_s[nl][c0 + 0] = xi.x + acc[0];
        s_s[nl][c0 + 1] = xi.y + acc[1];
        s_s[nl][c0 + 2] = xi.z + acc[2];
        s_s[nl][c0 + 3] = xi.w + acc[3];
    }
    __syncthreads();

    // Linear1 + BN + ReLU: each lane computes OC of 16 outputs
    if (i < N) {
#pragma unroll
        for (int o = 0; o < OC; ++o) {
            int j = lane * OC + o;
            float a = s_ba[j];
#pragma unroll
            for (int k = 0; k < DIN; ++k) a = fmaf(s_s[nl][k], s_wa[k * 16 + j], a);
            a = a * s_scale[j] + s_shift[j];
            s_h[nl][j] = a > 0.f ? a : 0.f;
        }
    }
    __syncthreads();

    // Linear2 + ReLU + coalesced store
    if (i < N) {
        float o_[OC];
#pragma unroll
        for (int o = 0; o < OC; ++o) {
            int j = lane * OC + o;
            float a = s_bb[j];
#pragma unroll
            for (int k = 0; k < 16; ++k) a = fmaf(s_h[nl][k], s_wb[k * 16 + j], a);
            o_[o] = a > 0.f ? a : 0.f;
        }
        if constexpr (OC == 4) {
            float4 ov = {o_[0], o_[1], o_[2], o_[3]};
            *(float4*)(hout + (size_t)i * 16 + lane * 4) = ov;
        } else {
            float2 ov = {o_[0], o_[1]};
            *(float2*)(hout + (size_t)i * 16 + lane * 2) = ov;
        }
    }
}

// ===========================================================================
// Head: out = relu(concat(h1,h2,h3) @ lw1 + lb1) @ lw2 + lb2.
// 4 lanes per node; each lane computes 16 of the 64 hidden units, partial
// outputs reduced across the group with shfl_xor.
// ===========================================================================
__global__ __launch_bounds__(256)
void final_kernel(const float* __restrict__ h1, const float* __restrict__ h2,
                  const float* __restrict__ h3,
                  const float* __restrict__ lw1, const float* __restrict__ lb1,
                  const float* __restrict__ lw2, const float* __restrict__ lb2,
                  float* __restrict__ out, int N) {
    constexpr int NPB = 64;
    __shared__ float s_lw1[48 * 64];   // 12 KB
    __shared__ float s_lw2[64 * 4];
    __shared__ float s_lb1[64];
    __shared__ float s_lb2[4];
    __shared__ float s_c[NPB][49];     // padded concat buffer

    int t = threadIdx.x;
    for (int idx = t; idx < 48 * 64; idx += 256) s_lw1[idx] = lw1[idx];
    s_lw2[t] = lw2[t];
    if (t < 64) s_lb1[t] = lb1[t];
    if (t < 4) s_lb2[t] = lb2[t];

    int nl = t >> 2;         // node within block
    int l  = t & 3;          // lane within group of 4 (same wave)
    int i  = blockIdx.x * NPB + nl;

    if (i < N) {
        float4 c1 = ((const float4*)(h1 + (size_t)i * 16))[l];
        float4 c2 = ((const float4*)(h2 + (size_t)i * 16))[l];
        float4 c3 = ((const float4*)(h3 + (size_t)i * 16))[l];
        s_c[nl][l * 4 + 0] = c1.x; s_c[nl][l * 4 + 1] = c1.y;
        s_c[nl][l * 4 + 2] = c1.z; s_c[nl][l * 4 + 3] = c1.w;
        s_c[nl][16 + l * 4 + 0] = c2.x; s_c[nl][16 + l * 4 + 1] = c2.y;
        s_c[nl][16 + l * 4 + 2] = c2.z; s_c[nl][16 + l * 4 + 3] = c2.w;
        s_c[nl][32 + l * 4 + 0] = c3.x; s_c[nl][32 + l * 4 + 1] = c3.y;
        s_c[nl][32 + l * 4 + 2] = c3.z; s_c[nl][32 + l * 4 + 3] = c3.w;
    }
    __syncthreads();

    float o0 = 0.f, o1 = 0.f, o2 = 0.f, o3 = 0.f;
    if (i < N) {
#pragma unroll 4
        for (int jj = 0; jj < 16; ++jj) {
            int j = l * 16 + jj;
            float a = s_lb1[j];
#pragma unroll
            for (int k = 0; k < 48; ++k) a = fmaf(s_c[nl][k], s_lw1[k * 64 + j], a);
            a = a > 0.f ? a : 0.f;
            o0 = fmaf(a, s_lw2[j * 4 + 0], o0);
            o1 = fmaf(a, s_lw2[j * 4 + 1], o1);
            o2 = fmaf(a, s_lw2[j * 4 + 2], o2);
            o3 = fmaf(a, s_lw2[j * 4 + 3], o3);
        }
    }
    // reduce across the 4 lanes of the group (same wave)
    o0 += __shfl_xor(o0, 1); o0 += __shfl_xor(o0, 2);
    o1 += __shfl_xor(o1, 1); o1 += __shfl_xor(o1, 2);
    o2 += __shfl_xor(o2, 1); o2 += __shfl_xor(o2, 2);
    o3 += __shfl_xor(o3, 1); o3 += __shfl_xor(o3, 2);
    if (i < N && l == 0) {
        float4 o = {o0 + s_lb2[0], o1 + s_lb2[1], o2 + s_lb2[2], o3 + s_lb2[3]};
        *(float4*)(out + (size_t)i * 4) = o;
    }
}

// ===========================================================================
// Launch
// ===========================================================================
extern "C" void kernel_launch(void* const* d_in, const int* in_sizes, int n_in,
                              void* d_out, int out_size, void* d_ws, size_t ws_size,
                              hipStream_t stream) {
    const float* x  = (const float*)d_in[0];
    const int*   ei = (const int*)d_in[1];
    const float* ea = (const float*)d_in[2];
    const int N = in_sizes[0] / 32;
    const int E = in_sizes[1] / 2;
    const int* srci = ei;
    const int* dsti = ei + E;

    const float* lw1 = (const float*)d_in[33];
    const float* lb1 = (const float*)d_in[34];
    const float* lw2 = (const float*)d_in[35];
    const float* lb2 = (const float*)d_in[36];

    const int nchunks = (N + 255) / 256;
    const int eblocks = (E + 255) / 256;

    // Workspace layout:
    char* p = (char*)d_ws;
    int*   rowstart   = (int*)p;   p += (size_t)(N + 1 + 3) / 4 * 16;
    int*   cursor     = (int*)p;   p += (size_t)(N + 3) / 4 * 16;    // aliases deg
    int*   bsum       = (int*)p;   p += (size_t)(nchunks + 3) / 4 * 16;
    int*   boff       = (int*)p;   p += (size_t)(nchunks + 3) / 4 * 16;
    int*   src_sorted = (int*)p;   p += (size_t)E * 4;
    int*   eid_sorted = (int*)p;   p += (size_t)E * 4;
    float* ea_sorted  = (float*)p; p += (size_t)E * 8 * 4;
    float* h1         = (float*)p; p += (size_t)N * 16 * 4;
    float* h2         = (float*)p; p += (size_t)N * 16 * 4;
    float* h3         = (float*)p; p += (size_t)N * 16 * 4;

    int* deg = cursor;

    // ---- Build CSR (counting sort by dst) ----
    hipMemsetAsync(deg, 0, (size_t)N * sizeof(int), stream);
    hist_kernel<<<eblocks, 256, 0, stream>>>(dsti, deg, E);
    blocksum_kernel<<<nchunks, 256, 0, stream>>>(deg, bsum, N);
    scanblocks_kernel<<<1, 512, 0, stream>>>(bsum, boff, nchunks, rowstart, N, E);
    scanfinal_kernel<<<nchunks, 256, 0, stream>>>(deg, boff, rowstart, cursor, N);
    scatter_kernel<<<eblocks, 256, 0, stream>>>(srci, dsti, cursor,
                                                src_sorted, eid_sorted, E);
    permute_ea_kernel<<<eblocks, 256, 0, stream>>>(ea, eid_sorted, ea_sorted, E);

    // ---- Layers (channel-parallel fused) ----
    gine_layer<32, 8><<<(N + 31) / 32, 256, 0, stream>>>(
        x, rowstart, src_sorted, ea_sorted,
        (const float*)d_in[3], (const float*)d_in[4],
        (const float*)d_in[5], (const float*)d_in[6],
        (const float*)d_in[7], (const float*)d_in[8],
        (const float*)d_in[9], (const float*)d_in[10],
        (const float*)d_in[11], (const float*)d_in[12], h1, N);

    gine_layer<16, 4><<<(N + 63) / 64, 256, 0, stream>>>(
        h1, rowstart, src_sorted, ea_sorted,
        (const float*)d_in[13], (const float*)d_in[14],
        (const float*)d_in[15], (const float*)d_in[16],
        (const float*)d_in[17], (const float*)d_in[18],
        (const float*)d_in[19], (const float*)d_in[20],
        (const float*)d_in[21], (const float*)d_in[22], h2, N);

    gine_layer<16, 4><<<(N + 63) / 64, 256, 0, stream>>>(
        h2, rowstart, src_sorted, ea_sorted,
        (const float*)d_in[23], (const float*)d_in[24],
        (const float*)d_in[25], (const float*)d_in[26],
        (const float*)d_in[27], (const float*)d_in[28],
        (const float*)d_in[29], (const float*)d_in[30],
        (const float*)d_in[31], (const float*)d_in[32], h3, N);

    // ---- Head ----
    final_kernel<<<(N + 63) / 64, 256, 0, stream>>>(
        h1, h2, h3, lw1, lb1, lw2, lb2, (float*)d_out, N);
}